// Round 2
// baseline (1690.390 us; speedup 1.0000x reference)
//
#include <hip/hip_runtime.h>

#define NPTS 2000000
#define FSTR 72    // feat LDS row stride (bf16 elems), 64 + 8 pad
#define HSTR 136   // h LDS row stride (bf16 elems), 128 + 8 pad

// packed workspace layout (ushort elements)
#define PK_PLANES 0
#define PK_W0 6912000
#define PK_W1 6920192
#define PK_W2 6936576
// total 6944768 elems = 13,889,536 bytes

typedef __attribute__((ext_vector_type(8))) short bf16x8;
typedef __attribute__((ext_vector_type(4))) float f32x4;
typedef unsigned short ushort_t;

__device__ __forceinline__ float bf2f(unsigned int u) {
    union { unsigned int i; float f; } v; v.i = u << 16; return v.f;
}
__device__ __forceinline__ unsigned short f2bf(float f) {
    union { float f; unsigned int i; } v; v.f = f;
    unsigned int r = v.i + 0x7FFFu + ((v.i >> 16) & 1u);
    return (unsigned short)(r >> 16);
}

// planes_s{i}: [3][16][150][W] fp32  ->  packed [3][150][W][16] bf16 (channel-last)
__global__ __launch_bounds__(256) void pack_planes(
        const float* __restrict__ s0, const float* __restrict__ s1,
        const float* __restrict__ s2, const float* __restrict__ s3,
        ushort_t* __restrict__ dst) {
    int id = blockIdx.x * 256 + threadIdx.x;
    const float* src; int W; size_t dbase; int rel;
    if (id < 28800)       { src = s0; W = 64;  dbase = 0;       rel = id; }
    else if (id < 86400)  { src = s1; W = 128; dbase = 460800;  rel = id - 28800; }
    else if (id < 201600) { src = s2; W = 256; dbase = 1382400; rel = id - 86400; }
    else if (id < 432000) { src = s3; W = 512; dbase = 3225600; rel = id - 201600; }
    else return;
    int p  = rel / (150 * W);
    int r2 = rel - p * 150 * W;              // y*W + x
    const float* sp = src + (size_t)p * 16 * 150 * W + r2;
    size_t cstride = (size_t)150 * W;
    unsigned int pk[8];
#pragma unroll
    for (int j = 0; j < 8; ++j) {
        unsigned int lo = f2bf(sp[(size_t)(2 * j) * cstride]);
        unsigned int hi = f2bf(sp[(size_t)(2 * j + 1) * cstride]);
        pk[j] = lo | (hi << 16);
    }
    uint4* d4 = reinterpret_cast<uint4*>(dst + dbase + ((size_t)p * 150 * W + r2) * 16);
    d4[0] = make_uint4(pk[0], pk[1], pk[2], pk[3]);
    d4[1] = make_uint4(pk[4], pk[5], pk[6], pk[7]);
}

// w0 [128][64], w1 [128][128], w2 [64][128] fp32 -> bf16, same layout
__global__ __launch_bounds__(256) void pack_weights(
        const float* __restrict__ w0, const float* __restrict__ w1,
        const float* __restrict__ w2, ushort_t* __restrict__ dst) {
    int id = blockIdx.x * 256 + threadIdx.x;   // 0..32767
    float v; size_t off;
    if (id < 8192)       { v = w0[id];         off = PK_W0 + id; }
    else if (id < 24576) { v = w1[id - 8192];  off = PK_W1 + (id - 8192); }
    else if (id < 32768) { v = w2[id - 24576]; off = PK_W2 + (id - 24576); }
    else return;
    dst[off] = f2bf(v);
}

__global__ __launch_bounds__(256) void fused_field_mlp(
        const float* __restrict__ pts, const ushort_t* __restrict__ packed,
        const float* __restrict__ b0, const float* __restrict__ b1,
        const float* __restrict__ b2, float* __restrict__ out) {
    __shared__ ushort_t feat[256 * FSTR];      // 36864 B
    __shared__ ushort_t hbuf[4][16 * HSTR];    // 17408 B, per-wave, reused h0->h1

    const int tid = threadIdx.x;
    const int pt  = blockIdx.x * 256 + tid;

    // ---------------- Phase A: gather features ----------------
    float4 q = make_float4(0.f, 0.f, 0.f, 0.f);
    if (pt < NPTS) q = reinterpret_cast<const float4*>(pts)[pt];
    float coord[3] = {q.x, q.y, q.z};
    float ct = q.w;

    // t -> H axis (shared across all 12 samples, H=150)
    float fy = (ct + 1.0f) * 0.5f * 149.0f;
    fy = fminf(fmaxf(fy, 0.0f), 149.0f);
    int iy0b = min((int)fy, 148);
    float wy = fy - (float)iy0b, omwy = 1.0f - wy;

#pragma unroll
    for (int s = 0; s < 4; ++s) {
        const int W = 64 << s;
        const size_t soff = (size_t)460800 * ((1u << s) - 1u);
        float acc[16];
#pragma unroll
        for (int c = 0; c < 16; ++c) acc[c] = 1.0f;
#pragma unroll
        for (int p = 0; p < 3; ++p) {
            float fx = (coord[p] + 1.0f) * 0.5f * (float)(W - 1);
            fx = fminf(fmaxf(fx, 0.0f), (float)(W - 1));
            int ix0b = min((int)fx, W - 2);
            float wx = fx - (float)ix0b, omwx = 1.0f - wx;
            const ushort_t* base = packed + soff + (size_t)p * 2400 * W
                                   + ((size_t)iy0b * W + ix0b) * 16;
            union RowU { uint4 v[4]; ushort_t u[32]; } r0, r1;
            const uint4* b4 = reinterpret_cast<const uint4*>(base);
            const uint4* b5 = reinterpret_cast<const uint4*>(base + (size_t)W * 16);
            r0.v[0] = b4[0]; r0.v[1] = b4[1]; r0.v[2] = b4[2]; r0.v[3] = b4[3];
            r1.v[0] = b5[0]; r1.v[1] = b5[1]; r1.v[2] = b5[2]; r1.v[3] = b5[3];
#pragma unroll
            for (int c = 0; c < 16; ++c) {
                float v00 = bf2f(r0.u[c]), v01 = bf2f(r0.u[16 + c]);
                float v10 = bf2f(r1.u[c]), v11 = bf2f(r1.u[16 + c]);
                float top = v00 * omwx + v01 * wx;
                float bot = v10 * omwx + v11 * wx;
                acc[c] *= top * omwy + bot * wy;
            }
        }
        unsigned int pk[8];
#pragma unroll
        for (int j = 0; j < 8; ++j)
            pk[j] = (unsigned int)f2bf(acc[2 * j]) | ((unsigned int)f2bf(acc[2 * j + 1]) << 16);
        uint4* f4 = reinterpret_cast<uint4*>(&feat[tid * FSTR + s * 16]);
        f4[0] = make_uint4(pk[0], pk[1], pk[2], pk[3]);
        f4[1] = make_uint4(pk[4], pk[5], pk[6], pk[7]);
    }

    __syncthreads();

    // ---------------- Phase B: MFMA MLP (each wave owns its 64 points) ----------------
    const int lane = tid & 63;
    const int w    = tid >> 6;
    const int l15  = lane & 15;
    const int quad = lane >> 4;
    const f32x4 zero = {0.f, 0.f, 0.f, 0.f};
    const ushort_t* w0p = packed + PK_W0;
    const ushort_t* w1p = packed + PK_W1;
    const ushort_t* w2p = packed + PK_W2;

    for (int sub = 0; sub < 4; ++sub) {
        const int pbase = w * 64 + sub * 16;

        // layer 1: feats[16x64] @ w0^T[64x128]
        bf16x8 a1[2];
#pragma unroll
        for (int k = 0; k < 2; ++k)
            a1[k] = *reinterpret_cast<bf16x8*>(&feat[(pbase + l15) * FSTR + k * 32 + quad * 8]);
        f32x4 acc1[8];
#pragma unroll
        for (int n = 0; n < 8; ++n) {
            f32x4 a = zero;
#pragma unroll
            for (int k = 0; k < 2; ++k) {
                bf16x8 b = *reinterpret_cast<const bf16x8*>(w0p + (n * 16 + l15) * 64 + k * 32 + quad * 8);
                a = __builtin_amdgcn_mfma_f32_16x16x32_bf16(a1[k], b, a, 0, 0, 0);
            }
            acc1[n] = a;
        }
#pragma unroll
        for (int n = 0; n < 8; ++n) {
            float bias = b0[n * 16 + l15];
#pragma unroll
            for (int r = 0; r < 4; ++r)
                hbuf[w][(quad * 4 + r) * HSTR + n * 16 + l15] = f2bf(fmaxf(acc1[n][r] + bias, 0.0f));
        }

        // layer 2: h0[16x128] @ w1^T[128x128]
        bf16x8 a2[4];
#pragma unroll
        for (int k = 0; k < 4; ++k)
            a2[k] = *reinterpret_cast<bf16x8*>(&hbuf[w][l15 * HSTR + k * 32 + quad * 8]);
        f32x4 acc2[8];
#pragma unroll
        for (int n = 0; n < 8; ++n) {
            f32x4 a = zero;
#pragma unroll
            for (int k = 0; k < 4; ++k) {
                bf16x8 b = *reinterpret_cast<const bf16x8*>(w1p + (n * 16 + l15) * 128 + k * 32 + quad * 8);
                a = __builtin_amdgcn_mfma_f32_16x16x32_bf16(a2[k], b, a, 0, 0, 0);
            }
            acc2[n] = a;
        }
        // h1 writes depend on acc2 <- mfma <- a2 loads (same-wave DS ordering), safe reuse
#pragma unroll
        for (int n = 0; n < 8; ++n) {
            float bias = b1[n * 16 + l15];
#pragma unroll
            for (int r = 0; r < 4; ++r)
                hbuf[w][(quad * 4 + r) * HSTR + n * 16 + l15] = f2bf(fmaxf(acc2[n][r] + bias, 0.0f));
        }

        // layer 3: h1[16x128] @ w2^T[128x64]
        bf16x8 a3[4];
#pragma unroll
        for (int k = 0; k < 4; ++k)
            a3[k] = *reinterpret_cast<bf16x8*>(&hbuf[w][l15 * HSTR + k * 32 + quad * 8]);
#pragma unroll
        for (int n = 0; n < 4; ++n) {
            f32x4 a = zero;
#pragma unroll
            for (int k = 0; k < 4; ++k) {
                bf16x8 b = *reinterpret_cast<const bf16x8*>(w2p + (n * 16 + l15) * 128 + k * 32 + quad * 8);
                a = __builtin_amdgcn_mfma_f32_16x16x32_bf16(a3[k], b, a, 0, 0, 0);
            }
            float bias = b2[n * 16 + l15];
            const int p0 = blockIdx.x * 256 + pbase + quad * 4;
#pragma unroll
            for (int r = 0; r < 4; ++r) {
                int prow = p0 + r;
                if (prow < NPTS)
                    out[(size_t)prow * 64 + n * 16 + l15] = a[r] + bias;
            }
        }
    }
}

extern "C" void kernel_launch(void* const* d_in, const int* in_sizes, int n_in,
                              void* d_out, int out_size, void* d_ws, size_t ws_size,
                              hipStream_t stream) {
    const float* pts = (const float*)d_in[0];
    const float* s0  = (const float*)d_in[1];
    const float* s1  = (const float*)d_in[2];
    const float* s2  = (const float*)d_in[3];
    const float* s3  = (const float*)d_in[4];
    const float* w0  = (const float*)d_in[5];
    const float* b0  = (const float*)d_in[6];
    const float* w1  = (const float*)d_in[7];
    const float* b1  = (const float*)d_in[8];
    const float* w2  = (const float*)d_in[9];
    const float* b2  = (const float*)d_in[10];
    ushort_t* packed = (ushort_t*)d_ws;   // 13,889,536 B used

    pack_planes<<<1688, 256, 0, stream>>>(s0, s1, s2, s3, packed);
    pack_weights<<<128, 256, 0, stream>>>(w0, w1, w2, packed);
    fused_field_mlp<<<(NPTS + 255) / 256, 256, 0, stream>>>(
        pts, packed, b0, b1, b2, (float*)d_out);
}